// Round 10
// baseline (293.039 us; speedup 1.0000x reference)
//
#include <hip/hip_runtime.h>

// N=50000, D=128 (both layers), K=256, EH=500000, ES=250000.
#define D_FEAT 128
#define K_DIM  256
#define EPB 4096    // edges per binA block (r6: smaller is WORSE)
#define PADL 136    // LDS leading dim (ushorts) for the 32x128 epilogue tile
#define BCAP 4096   // arena slots per bucket (mean 2560, >25 sigma headroom)

// ---- fragment-major layouts (eliminates 64-line address divergence in GEMMs) ----
// Wb (layer L, NT tiles): slot ((k0*NT + T)*64 + lane) * 8 shorts
// z  (A operand):        slot ((G*8 + k0)*64 + lane) * 8 shorts,  G = row group of 16

typedef __attribute__((ext_vector_type(8))) short bf16x8;
typedef __attribute__((ext_vector_type(4))) float f32x4;
typedef __attribute__((ext_vector_type(2))) float f32x2;

__device__ __forceinline__ unsigned short f2b(float f) {
    union { float f; unsigned u; } cv; cv.f = f;
    return (unsigned short)((cv.u + 0x7fffu + ((cv.u >> 16) & 1u)) >> 16);
}

__device__ __forceinline__ unsigned pack2(float lo, float hi) {
    return (unsigned)f2b(lo) | ((unsigned)f2b(hi) << 16);
}

__device__ __forceinline__ uint4 pack8(float4 a, float4 b) {
    return make_uint4(pack2(a.x, a.y), pack2(a.z, a.w), pack2(b.x, b.y), pack2(b.z, b.w));
}

__device__ __forceinline__ f32x2 up2(unsigned u) {
    union { unsigned u; float f; } lo, hi;
    lo.u = u << 16; hi.u = u & 0xffff0000u;
    f32x2 r; r.x = lo.f; r.y = hi.f; return r;
}

__device__ __forceinline__ void addu4p(f32x2* a, uint4 v) {
    a[0] += up2(v.x); a[1] += up2(v.y); a[2] += up2(v.z); a[3] += up2(v.w);
}

__device__ __forceinline__ float blo(unsigned u) { union { unsigned u; float f; } c; c.u = u << 16; return c.f; }
__device__ __forceinline__ float bhi(unsigned u) { union { unsigned u; float f; } c; c.u = u & 0xffff0000u; return c.f; }

// edge-array offset within the concatenated [H0|S0|H1|S1] space
__device__ __forceinline__ long yoff(int y, int EH, int ES) {
    return (long)((y + 1) >> 1) * EH + (long)(y >> 1) * ES;
}

// ---------------- arena cursor init (replaces memset + histB + pre-scan) ----------------
__global__ __launch_bounds__(256)
void initCur(int* __restrict__ bcur, int total) {
    int i = blockIdx.x * 256 + threadIdx.x;
    if (i < total) bcur[i] = i * BCAP;
}

// ---------------- fused binA(arena) + prep_static + conv_weights ----------------
// Blocks [0, 4*binb): record scatter into per-bucket arena regions (latency/atomic bound).
// Blocks [4*binb, +prepb): bf16 prep (streaming, BW-bound).  Blocks [.., +16): weights.
// Complementary bottlenecks overlap (r7: 49us vs ~63 serial). dst re-read in pass 2
// is CHEAPER than register staging (r8: dv[16] cost 3.5us via VGPR 28->36).
__global__ __launch_bounds__(256)
void binPrep(const int* __restrict__ hs0, const int* __restrict__ hd0,
             const int* __restrict__ ss0, const int* __restrict__ sd0,
             const int* __restrict__ hs1, const int* __restrict__ hd1,
             const int* __restrict__ ss1, const int* __restrict__ sd1,
             int EH, int ES, int* __restrict__ bcur, unsigned* __restrict__ arena,
             int nb2, int binb,
             const float4* __restrict__ x, const float4* __restrict__ hbar0,
             const float4* __restrict__ hbar1,
             uint4* __restrict__ hb0, uint4* __restrict__ db0,
             uint4* __restrict__ hb1, uint4* __restrict__ z, int n16, int prepb,
             const float* __restrict__ W0, unsigned short* __restrict__ WbF0,
             const float* __restrict__ W1, unsigned short* __restrict__ WbF1) {
    __shared__ int cnt[256];
    int bid = blockIdx.x;
    int t = threadIdx.x;

    if (bid < 4 * binb) {
        int y = bid / binb, c = bid % binb;
        const int* src = (y == 0) ? hs0 : (y == 1) ? ss0 : (y == 2) ? hs1 : ss1;
        const int* dst = (y == 0) ? hd0 : (y == 1) ? sd0 : (y == 2) ? hd1 : sd1;
        int E = (y & 1) ? ES : EH;

        cnt[t] = 0;
        __syncthreads();
        int i0 = c * EPB;
        #pragma unroll
        for (int j = 0; j < 16; ++j) {
            int i = i0 + j * 256 + t;
            if (i < E) atomicAdd(&cnt[dst[i] >> 8], 1);
        }
        __syncthreads();
        int cc = cnt[t];
        __syncthreads();
        // reserve contiguous chunk in bucket t's arena region (absolute slot index)
        if (t < nb2 && cc > 0) cnt[t] = atomicAdd(&bcur[y * nb2 + t], cc);
        __syncthreads();
        #pragma unroll
        for (int j = 0; j < 16; ++j) {
            int i = i0 + j * 256 + t;
            if (i < E) {
                int dd = dst[i];
                int slot = atomicAdd(&cnt[dd >> 8], 1);
                arena[slot] = (unsigned)src[i] | ((unsigned)(dd & 255) << 24);
            }
        }
    } else if (bid < 4 * binb + prepb) {
        int i = (bid - 4 * binb) * 256 + t;
        if (i >= n16) return;
        float4 xa = x[i * 2],     xb = x[i * 2 + 1];
        float4 ba = hbar0[i * 2], bb = hbar0[i * 2 + 1];
        float4 ca = hbar1[i * 2], cb = hbar1[i * 2 + 1];
        hb0[i] = pack8(ba, bb);
        db0[i] = pack8(make_float4(xa.x - ba.x, xa.y - ba.y, xa.z - ba.z, xa.w - ba.w),
                       make_float4(xb.x - bb.x, xb.y - bb.y, xb.z - bb.z, xb.w - bb.w));
        hb1[i] = pack8(ca, cb);
        int g = i >> 4, seg = i & 15;
        int G = g >> 4, r = g & 15, k0 = seg >> 2, kq = seg & 3;
        z[((size_t)G * 8 + k0) * 64 + kq * 16 + r] = pack8(xa, xb);   // fragment-major
    } else {
        int i = (bid - 4 * binb - prepb) * 256 + t;
        if (i < 4096) {
            int k0 = i >> 9, T = (i >> 6) & 7, lane = i & 63;
            int col = T * 16 + (lane & 15);
            int kb = k0 * 32 + (lane >> 4) * 8;
            const float* src = W0 + (size_t)col * 256 + kb;
            unsigned short* dst = WbF0 + (size_t)i * 8;
            #pragma unroll
            for (int e = 0; e < 8; ++e) dst[e] = f2b(src[e]);
        }
        if (i < 1536) {
            int k0 = i / 192, rem = i % 192;
            int T = rem >> 6, lane = rem & 63;
            int col = T * 16 + (lane & 15);
            int kb = k0 * 32 + (lane >> 4) * 8;
            unsigned short* dst = WbF1 + (size_t)i * 8;
            #pragma unroll
            for (int e = 0; e < 8; ++e)
                dst[e] = (col < 47) ? f2b(W1[(size_t)col * 256 + kb + e]) : (unsigned short)0;
        }
    }
}

// ---------------- place: arena bucket -> compact srcAll + node-level rp ----------------
// Computes its own bucket base via LDS scan of bcur (scanB2 kernel eliminated).
// LDS-light (2KB): no record cache, arena re-read hits L2/L3 (written 1 dispatch ago).
__device__ __forceinline__ void doPlace(int y, int b,
                                        const unsigned* __restrict__ arena,
                                        const int* __restrict__ bcur,
                                        int* __restrict__ rpAll, int* __restrict__ srcAll,
                                        int EH, int ES, int n, int nb2,
                                        int* cnt, int* sh) {
    int E = (y & 1) ? ES : EH;
    int t = threadIdx.x;
    // bucket counts for this etype -> inclusive scan -> this bucket's global base e0
    int cb = (t < nb2) ? (bcur[y * nb2 + t] - (y * nb2 + t) * BCAP) : 0;
    sh[t] = cb;
    __syncthreads();
    for (int o = 1; o < 256; o <<= 1) {
        int v = (t >= o) ? sh[t - o] : 0;
        __syncthreads();
        sh[t] += v;
        __syncthreads();
    }
    int e0 = (b > 0) ? sh[b - 1] : 0;
    int ybb = y * nb2 + b;
    int ne = bcur[ybb] - ybb * BCAP;
    const unsigned* rb = arena + (size_t)ybb * BCAP;
    int* rp = rpAll + (size_t)y * (n + 1);
    int* sb = srcAll + yoff(y, EH, ES);
    int nodeBase = b << 8;

    __syncthreads();
    cnt[t] = 0;
    __syncthreads();
    for (int e = t; e < ne; e += 256)
        atomicAdd(&cnt[rb[e] >> 24], 1);
    __syncthreads();
    sh[t] = cnt[t];
    __syncthreads();
    for (int o = 1; o < 256; o <<= 1) {
        int v = (t >= o) ? sh[t - o] : 0;
        __syncthreads();
        sh[t] += v;
        __syncthreads();
    }
    int base = e0 + (t ? sh[t - 1] : 0);
    if (nodeBase + t < n) rp[nodeBase + t] = base;
    if (b == 0 && t == 0) rp[n] = E;
    cnt[t] = base;
    __syncthreads();
    for (int e = t; e < ne; e += 256) {
        unsigned r = rb[e];
        int p = atomicAdd(&cnt[r >> 24], 1);
        sb[p] = (int)(r & 0x00FFFFFFu);
    }
}

// etypes 0,1 (layer-0 CSR): standalone, must precede layer-0 aggregation.
__global__ __launch_bounds__(256)
void placeLow(const unsigned* __restrict__ arena, const int* __restrict__ bcur,
              int* __restrict__ rpAll, int* __restrict__ srcAll,
              int EH, int ES, int n, int nb2) {
    __shared__ int cnt[256];
    __shared__ int sh[256];
    doPlace(blockIdx.y, blockIdx.x, arena, bcur, rpAll, srcAll, EH, ES, n, nb2, cnt, sh);
}

// ---------------- fused: layer-0 aggregation || place(etypes 2,3) ----------------
// Blocks [0, aggb): aggregate_z for layer 0 (gather-latency bound, proven 43.2us).
// Blocks [aggb, +2*nb2): layer-1 CSR placement (LDS-atomic/scatter) -- hidden under agg.
__global__ __launch_bounds__(256)
void aggPlace(const uint4* __restrict__ HB, const uint4* __restrict__ DB,
              const int* __restrict__ rpH, const int* __restrict__ srcH,
              const int* __restrict__ rpS, const int* __restrict__ srcS,
              uint4* __restrict__ z, int n, int aggb,
              const unsigned* __restrict__ arena, const int* __restrict__ bcur,
              int* __restrict__ rpAll, int* __restrict__ srcAll,
              int EH, int ES, int nb2) {
    __shared__ int cnt[256];
    __shared__ int sh[256];
    int bid = blockIdx.x;
    if (bid >= aggb) {
        int r = bid - aggb;
        doPlace(2 + r / nb2, r % nb2, arena, bcur, rpAll, srcAll, EH, ES, n, nb2, cnt, sh);
        return;
    }

    int g = bid * 4 + (threadIdx.x >> 6);
    if (g >= n) return;
    int lane = threadIdx.x & 63;
    int j = lane >> 4, l = lane & 15;

    int hb_ = rpH[g], he = rpH[g + 1];
    int sb  = rpS[g], se = rpS[g + 1];
    int dH = he - hb_, dS = se - sb;
    int nIt = max((dH + 7) >> 3, (dS + 7) >> 3);

    f32x2 a[4] = {};
    f32x2 d[4] = {};

    int iH1 = hb_ + j, iH2 = hb_ + 4 + j;
    int iS1 = sb + j,  iS2 = sb + 4 + j;
    int sH1 = 0, sH2 = 0, sS1 = 0, sS2 = 0;
    if (iH1 < he) sH1 = srcH[iH1];
    if (iH2 < he) sH2 = srcH[iH2];
    if (iS1 < se) sS1 = srcS[iS1];
    if (iS2 < se) sS2 = srcS[iS2];

    for (int it = 0; it < nIt; ++it) {
        uint4 h1 = make_uint4(0, 0, 0, 0), h2 = make_uint4(0, 0, 0, 0);
        uint4 s1 = make_uint4(0, 0, 0, 0), s2 = make_uint4(0, 0, 0, 0);
        if (iH1 < he) h1 = HB[(size_t)sH1 * 16 + l];
        if (iH2 < he) h2 = HB[(size_t)sH2 * 16 + l];
        if (iS1 < se) s1 = DB[(size_t)sS1 * 16 + l];
        if (iS2 < se) s2 = DB[(size_t)sS2 * 16 + l];
        iH1 += 8; iH2 += 8; iS1 += 8; iS2 += 8;
        if (iH1 < he) sH1 = srcH[iH1];
        if (iH2 < he) sH2 = srcH[iH2];
        if (iS1 < se) sS1 = srcS[iS1];
        if (iS2 < se) sS2 = srcS[iS2];
        addu4p(a, h1); addu4p(a, h2);
        addu4p(d, s1); addu4p(d, s2);
    }

    float rH = 1.0f / fmaxf((float)dH, 1.0f);
    float rS = 1.0f / fmaxf((float)dS, 1.0f);
    float s[8];
    #pragma unroll
    for (int i = 0; i < 4; ++i) {
        float v0 = a[i].x * rH + d[i].x * rS;
        float v1 = a[i].y * rH + d[i].y * rS;
        v0 += __shfl_xor(v0, 16);
        v0 += __shfl_xor(v0, 32);
        v1 += __shfl_xor(v1, 16);
        v1 += __shfl_xor(v1, 32);
        s[2 * i] = v0;
        s[2 * i + 1] = v1;
    }
    if (j == 0) {
        uint4 rv = make_uint4(pack2(s[0], s[1]), pack2(s[2], s[3]),
                              pack2(s[4], s[5]), pack2(s[6], s[7]));
        size_t slot = ((size_t)(g >> 4) * 8 + 4 + (l >> 2)) * 64 + (l & 3) * 16 + (g & 15);
        z[slot] = rv;
    }
}

// ---------------- fused: gemm_l0 (streaming/MFMA) || layer-1 H-mean (gather) ----------------
__global__ __launch_bounds__(256, 2)
void gemmAgg(const unsigned short* __restrict__ Z, const unsigned short* __restrict__ Wb,
             const float* __restrict__ bias, const float* __restrict__ hbar1,
             unsigned short* __restrict__ db1, unsigned short* __restrict__ zl, int n,
             int gemmb,
             const uint4* __restrict__ HB1, const int* __restrict__ rpH1,
             const int* __restrict__ srcH1, uint4* __restrict__ hm1) {
    __shared__ unsigned short hl[32 * PADL];
    int bid = blockIdx.x;
    int tid = threadIdx.x;
    int lane = tid & 63;

    if (bid < gemmb) {
        int wave = tid >> 6;
        int rt = wave >> 1;
        int ch = wave & 1;
        int m0 = bid * 32;
        int cl = lane & 15;
        int kq = lane >> 4;

        const short* Af = (const short*)Z;
        const short* Bf = (const short*)Wb;
        size_t G = (size_t)(m0 >> 4) + rt;

        bf16x8 aF[8];
        #pragma unroll
        for (int k0 = 0; k0 < 8; ++k0)
            aF[k0] = *(const bf16x8*)(Af + ((G * 8 + k0) * 64 + lane) * 8);

        f32x4 acc[4] = {};
        bf16x8 bF[2][4];
        #pragma unroll
        for (int t = 0; t < 4; ++t)
            bF[0][t] = *(const bf16x8*)(Bf + ((size_t)((ch * 4 + t)) * 64 + lane) * 8);

        #pragma unroll
        for (int k0 = 0; k0 < 8; ++k0) {
            int cur = k0 & 1, nxt = cur ^ 1;
            if (k0 < 7) {
                #pragma unroll
                for (int t = 0; t < 4; ++t)
                    bF[nxt][t] = *(const bf16x8*)(Bf + ((size_t)(((k0 + 1) * 8 + ch * 4 + t)) * 64 + lane) * 8);
            }
            #pragma unroll
            for (int t = 0; t < 4; ++t)
                acc[t] = __builtin_amdgcn_mfma_f32_16x16x32_bf16(aF[k0], bF[cur][t], acc[t], 0, 0, 0);
        }

        #pragma unroll
        for (int t = 0; t < 4; ++t) {
            int c = ch * 64 + t * 16 + cl;
            float bv = bias[c];
            #pragma unroll
            for (int r = 0; r < 4; ++r) {
                int row = rt * 16 + kq * 4 + r;
                hl[row * PADL + c] = f2b(fmaxf(acc[t][r] + bv, 0.0f));
            }
        }
        __syncthreads();

        // zl (layer-1 A operand) written FRAGMENT-MAJOR: 512 slots of 16B, coalesced.
        #pragma unroll
        for (int s = 0; s < 2; ++s) {
            int ls = tid + s * 256;
            int gi = ls >> 8, k0 = (ls >> 6) & 3, ln = ls & 63;
            int rl = gi * 16 + (ln & 15);
            int col = k0 * 32 + (ln >> 4) * 8;
            int m = m0 + rl;
            if (m < n) {
                uint4 v = *(const uint4*)(hl + rl * PADL + col);
                ((uint4*)zl)[((size_t)(m0 >> 4) + gi) * 8 * 64 + (size_t)k0 * 64 + ln] = v;
            }
        }

        // db1 = bf16(h - hbar1), row-major (gather target), coalesced
        int row  = tid >> 3;
        int col  = (tid & 7) * 16;
        int m    = m0 + row;
        if (m < n) {
            const uint4* hr = (const uint4*)(hl + row * PADL + col);
            uint4 v0 = hr[0];
            uint4 v1 = hr[1];
            const float4* hb = (const float4*)(hbar1 + (size_t)m * 128 + col);
            float4 h0 = hb[0], h1 = hb[1], h2 = hb[2], h3 = hb[3];
            uint4 d0, d1;
            d0.x = pack2(blo(v0.x) - h0.x, bhi(v0.x) - h0.y);
            d0.y = pack2(blo(v0.y) - h0.z, bhi(v0.y) - h0.w);
            d0.z = pack2(blo(v0.z) - h1.x, bhi(v0.z) - h1.y);
            d0.w = pack2(blo(v0.w) - h1.z, bhi(v0.w) - h1.w);
            d1.x = pack2(blo(v1.x) - h2.x, bhi(v1.x) - h2.y);
            d1.y = pack2(blo(v1.y) - h2.z, bhi(v1.y) - h2.w);
            d1.z = pack2(blo(v1.z) - h3.x, bhi(v1.z) - h3.y);
            d1.w = pack2(blo(v1.w) - h3.z, bhi(v1.w) - h3.w);
            uint4* dp = (uint4*)(db1 + (size_t)m * 128 + col);
            dp[0] = d0;
            dp[1] = d1;
        }
    } else {
        // ---- layer-1: history mean only -> hm1 (row-major bf16). 4 H-slots/lane. ----
        int g = (bid - gemmb) * 4 + (tid >> 6);
        if (g >= n) return;
        int j = lane >> 4, l = lane & 15;
        int hb_ = rpH1[g], he = rpH1[g + 1];
        int dH = he - hb_;
        int nIt = (dH + 15) >> 4;

        f32x2 a[4] = {};
        int iH1 = hb_ + j, iH2 = hb_ + 4 + j, iH3 = hb_ + 8 + j, iH4 = hb_ + 12 + j;
        int sH1 = 0, sH2 = 0, sH3 = 0, sH4 = 0;
        if (iH1 < he) sH1 = srcH1[iH1];
        if (iH2 < he) sH2 = srcH1[iH2];
        if (iH3 < he) sH3 = srcH1[iH3];
        if (iH4 < he) sH4 = srcH1[iH4];

        for (int it = 0; it < nIt; ++it) {
            uint4 h1 = make_uint4(0,0,0,0), h2 = make_uint4(0,0,0,0);
            uint4 h3 = make_uint4(0,0,0,0), h4 = make_uint4(0,0,0,0);
            if (iH1 < he) h1 = HB1[(size_t)sH1 * 16 + l];
            if (iH2 < he) h2 = HB1[(size_t)sH2 * 16 + l];
            if (iH3 < he) h3 = HB1[(size_t)sH3 * 16 + l];
            if (iH4 < he) h4 = HB1[(size_t)sH4 * 16 + l];
            iH1 += 16; iH2 += 16; iH3 += 16; iH4 += 16;
            if (iH1 < he) sH1 = srcH1[iH1];
            if (iH2 < he) sH2 = srcH1[iH2];
            if (iH3 < he) sH3 = srcH1[iH3];
            if (iH4 < he) sH4 = srcH1[iH4];
            addu4p(a, h1); addu4p(a, h2); addu4p(a, h3); addu4p(a, h4);
        }

        float rH = 1.0f / fmaxf((float)dH, 1.0f);
        float s[8];
        #pragma unroll
        for (int i = 0; i < 4; ++i) {
            float v0 = a[i].x * rH;
            float v1 = a[i].y * rH;
            v0 += __shfl_xor(v0, 16);
            v0 += __shfl_xor(v0, 32);
            v1 += __shfl_xor(v1, 16);
            v1 += __shfl_xor(v1, 32);
            s[2 * i] = v0;
            s[2 * i + 1] = v1;
        }
        if (j == 0) {
            uint4 rv = make_uint4(pack2(s[0], s[1]), pack2(s[2], s[3]),
                                  pack2(s[4], s[5]), pack2(s[6], s[7]));
            hm1[(size_t)g * 16 + l] = rv;
        }
    }
}

// ---------------- layer-1 sampled aggregation (post-gemmAgg; proven r4) ----------------
__global__ __launch_bounds__(256)
void agg_s1(const uint4* __restrict__ DB1, const int* __restrict__ rpS,
            const int* __restrict__ srcS, const uint4* __restrict__ hm1,
            uint4* __restrict__ z, int n) {
    int g = blockIdx.x * 4 + (threadIdx.x >> 6);
    if (g >= n) return;
    int lane = threadIdx.x & 63;
    int j = lane >> 4, l = lane & 15;

    int sb = rpS[g], se = rpS[g + 1];
    int dS = se - sb;
    int nIt = (dS + 7) >> 3;

    f32x2 d[4] = {};
    int iS1 = sb + j, iS2 = sb + 4 + j;
    int sS1 = 0, sS2 = 0;
    if (iS1 < se) sS1 = srcS[iS1];
    if (iS2 < se) sS2 = srcS[iS2];

    for (int it = 0; it < nIt; ++it) {
        uint4 s1 = make_uint4(0,0,0,0), s2 = make_uint4(0,0,0,0);
        if (iS1 < se) s1 = DB1[(size_t)sS1 * 16 + l];
        if (iS2 < se) s2 = DB1[(size_t)sS2 * 16 + l];
        iS1 += 8; iS2 += 8;
        if (iS1 < se) sS1 = srcS[iS1];
        if (iS2 < se) sS2 = srcS[iS2];
        addu4p(d, s1); addu4p(d, s2);
    }

    float rS = 1.0f / fmaxf((float)dS, 1.0f);
    float s[8];
    #pragma unroll
    for (int i = 0; i < 4; ++i) {
        float v0 = d[i].x * rS;
        float v1 = d[i].y * rS;
        v0 += __shfl_xor(v0, 16);
        v0 += __shfl_xor(v0, 32);
        v1 += __shfl_xor(v1, 16);
        v1 += __shfl_xor(v1, 32);
        s[2 * i] = v0;
        s[2 * i + 1] = v1;
    }
    if (j == 0) {
        uint4 hm = hm1[(size_t)g * 16 + l];
        s[0] += blo(hm.x); s[1] += bhi(hm.x);
        s[2] += blo(hm.y); s[3] += bhi(hm.y);
        s[4] += blo(hm.z); s[5] += bhi(hm.z);
        s[6] += blo(hm.w); s[7] += bhi(hm.w);
        uint4 rv = make_uint4(pack2(s[0], s[1]), pack2(s[2], s[3]),
                              pack2(s[4], s[5]), pack2(s[6], s[7]));
        size_t slot = ((size_t)(g >> 4) * 8 + 4 + (l >> 2)) * 64 + (l & 3) * 16 + (g & 15);
        z[slot] = rv;
    }
}

// ---------------- MFMA GEMM layer 1 -> f32 out ----------------
template<int NT>
__global__ __launch_bounds__(128, 2)
void gemm_mfma(const unsigned short* __restrict__ Z, const unsigned short* __restrict__ Wb,
               const float* __restrict__ bias, float* __restrict__ out, int n, int COLS) {
    int wave = threadIdx.x >> 6;
    int lane = threadIdx.x & 63;
    int m0 = blockIdx.x * 32 + wave * 16;
    int cl = lane & 15;
    int kq = lane >> 4;

    const short* Af = (const short*)Z;
    const short* Bf = (const short*)Wb;
    size_t G = (size_t)(m0 >> 4);

    bf16x8 aF[8];
    #pragma unroll
    for (int k0 = 0; k0 < 8; ++k0)
        aF[k0] = *(const bf16x8*)(Af + ((G * 8 + k0) * 64 + lane) * 8);

    f32x4 acc[NT] = {};
    bf16x8 bF[2][NT];
    #pragma unroll
    for (int t = 0; t < NT; ++t)
        bF[0][t] = *(const bf16x8*)(Bf + ((size_t)(0 * NT + t) * 64 + lane) * 8);

    #pragma unroll
    for (int k0 = 0; k0 < 8; ++k0) {
        int cur = k0 & 1, nxt = cur ^ 1;
        if (k0 < 7) {
            #pragma unroll
            for (int t = 0; t < NT; ++t)
                bF[nxt][t] = *(const bf16x8*)(Bf + ((size_t)((k0 + 1) * NT + t) * 64 + lane) * 8);
        }
        #pragma unroll
        for (int t = 0; t < NT; ++t)
            acc[t] = __builtin_amdgcn_mfma_f32_16x16x32_bf16(aF[k0], bF[cur][t], acc[t], 0, 0, 0);
    }

    int rg = kq * 4;
    #pragma unroll
    for (int t = 0; t < NT; ++t) {
        int c = t * 16 + cl;
        if (c >= COLS) continue;
        float bv = bias[c];
        #pragma unroll
        for (int r = 0; r < 4; ++r) {
            int m = m0 + rg + r;
            if (m < n) out[(size_t)m * COLS + c] = fmaxf(acc[t][r] + bv, 0.f);
        }
    }
}

extern "C" void kernel_launch(void* const* d_in, const int* in_sizes, int n_in,
                              void* d_out, int out_size, void* d_ws, size_t ws_size,
                              hipStream_t stream) {
    const float* x     = (const float*)d_in[0];
    const float* hbar0 = (const float*)d_in[1];
    const float* hbar1 = (const float*)d_in[2];
    const float* W0    = (const float*)d_in[3];
    const float* b0    = (const float*)d_in[4];
    const float* W1    = (const float*)d_in[5];
    const float* b1    = (const float*)d_in[6];
    const int* hs0 = (const int*)d_in[7];
    const int* hd0 = (const int*)d_in[8];
    const int* ss0 = (const int*)d_in[9];
    const int* sd0 = (const int*)d_in[10];
    const int* hs1 = (const int*)d_in[11];
    const int* hd1 = (const int*)d_in[12];
    const int* ss1 = (const int*)d_in[13];
    const int* sd1 = (const int*)d_in[14];

    const int n   = in_sizes[0] / D_FEAT;   // 50000
    const int EH  = in_sizes[7];            // 500000
    const int ES  = in_sizes[9];            // 250000
    const int nb2 = (n + 255) / 256;        // 196 dst buckets per etype

    // ---- workspace layout ----
    int* bcur      = (int*)d_ws;                        // 4*nb2 arena cursors
    int* rpAll     = bcur + 4 * nb2;                    // 4*(n+1)
    int* srcAll    = rpAll + 4 * (size_t)(n + 1);       // 2EH+2ES
    unsigned* arena = (unsigned*)(srcAll + 2 * (size_t)EH + 2 * (size_t)ES); // 4*nb2*BCAP
    size_t int_words = (size_t)4 * nb2 + 4 * (size_t)(n + 1)
                     + 2 * (size_t)EH + 2 * (size_t)ES + (size_t)4 * nb2 * BCAP;
    int_words = (int_words + 3) & ~(size_t)3;                          // 16 B align
    unsigned short* hb0 = (unsigned short*)((int*)d_ws + int_words);   // n*128 bf16
    unsigned short* db0 = hb0 + (size_t)n * D_FEAT;                    // n*128 bf16
    unsigned short* hb1 = db0 + (size_t)n * D_FEAT;                    // n*128 bf16
    unsigned short* db1 = hb1 + (size_t)n * D_FEAT;                    // n*128 bf16
    unsigned short* z   = db1 + (size_t)n * D_FEAT;                    // n*256 bf16 (+1 pad group)
    unsigned short* Wb0 = z + (size_t)n * K_DIM + 4096;                // 128*256 (pad: tail group reads)
    unsigned short* Wb1 = Wb0 + 128 * 256;                             // 64*256
    unsigned short* hm1 = Wb1 + 64 * 256;                              // n*128 bf16 (layer-1 hist mean)

    const int* rpH0 = rpAll;
    const int* rpS0 = rpAll + (size_t)(n + 1);
    const int* rpH1 = rpAll + 2 * (size_t)(n + 1);
    const int* rpS1 = rpAll + 3 * (size_t)(n + 1);
    int* srcH0 = srcAll;
    int* srcS0 = srcAll + (size_t)EH;
    int* srcH1 = srcAll + (size_t)EH + ES;
    int* srcS1 = srcAll + 2 * (size_t)EH + ES;

    dim3 blk(256);
    int binb  = (EH + EPB - 1) / EPB;       // 123 blocks/etype
    int prepb = ((n * 16) + 255) / 256;     // 3125
    int aggb  = (n + 3) / 4;                // 12500
    int gemmb0 = (n + 31) / 32;             // 1563
    int gemmb1 = (n + 31) / 32;

    // ---- CSR build (arena) + static prep ----
    initCur<<<4, blk, 0, stream>>>(bcur, 4 * nb2);
    binPrep<<<4 * binb + prepb + 16, blk, 0, stream>>>(
        hs0, hd0, ss0, sd0, hs1, hd1, ss1, sd1, EH, ES, bcur, arena, nb2, binb,
        (const float4*)x, (const float4*)hbar0, (const float4*)hbar1,
        (uint4*)hb0, (uint4*)db0, (uint4*)hb1, (uint4*)z, n * 16, prepb,
        W0, Wb0, W1, Wb1);
    placeLow<<<dim3(nb2, 2), blk, 0, stream>>>(arena, bcur, rpAll, srcAll, EH, ES, n, nb2);

    // ---------------- Layer 0 aggregation || layer-1 CSR placement ----------------
    aggPlace<<<aggb + 2 * nb2, blk, 0, stream>>>((const uint4*)hb0, (const uint4*)db0,
                                                 rpH0, srcH0, rpS0, srcS0, (uint4*)z, n, aggb,
                                                 arena, bcur, rpAll, srcAll, EH, ES, nb2);

    // ---------------- gemm layer 0 || layer-1 history mean ----------------
    gemmAgg<<<gemmb0 + aggb, blk, 0, stream>>>(z, Wb0, b0, hbar1, db1, z, n, gemmb0,
                                               (const uint4*)hb1, rpH1, srcH1, (uint4*)hm1);

    // ---------------- Layer 1: sampled aggregation + GEMM ----------------
    agg_s1<<<aggb, blk, 0, stream>>>((const uint4*)db1, rpS1, srcS1, (const uint4*)hm1,
                                     (uint4*)z, n);
    gemm_mfma<3><<<gemmb1, dim3(128), 0, stream>>>(z, Wb1, b1, (float*)d_out, n, 47);
}